// Round 7
// baseline (357.297 us; speedup 1.0000x reference)
//
#include <hip/hip_runtime.h>

#define N_RAYS 16384
#define MAX_STEPS 512
#define GRID_R 128
#define N_CELLS (GRID_R * GRID_R * GRID_R) /* 2097152 */
#define NS (N_RAYS * MAX_STEPS)            /* 8388608 samples */

// ws layout (bytes):
//   [0)       flag (1 int)
//   [1024)    counts (16384 ints = 65536 B)
//   [131072)  bit grid (N_CELLS/8 = 262144 B)
#define WS_COUNTS_OFF 1024
#define WS_BITS_OFF 131072
#define WS_NEEDED (WS_BITS_OFF + N_CELLS / 8)

#define SAMPLE_GRID 1024   /* persistent: 4 blocks/CU x 256 CU, 16 rays/block */

typedef float f4v __attribute__((ext_vector_type(4)));
typedef int   i4v __attribute__((ext_vector_type(4)));

// ---------------------------------------------------------------------------
// Fallback detect (only launched when in_sizes[3] is ambiguous, i.e. not
// 4*N_CELLS bytes). flag: 0 = 4-byte words, 2 = bytes.
// ---------------------------------------------------------------------------
__global__ void detect_bw(const unsigned int* __restrict__ occ, int* __restrict__ flag) {
    __shared__ int okw;
    if (threadIdx.x == 0) okw = 1;
    __syncthreads();
    for (int i = threadIdx.x; i < 1024; i += blockDim.x) {
        const unsigned int v = occ[i];
        if (v != 0u && v != 1u && v != 0x3f800000u) atomicAnd(&okw, 0);
    }
    __syncthreads();
    if (threadIdx.x == 0) flag[0] = okw ? 0 : 2;
}

// ---------------------------------------------------------------------------
// Compress occ grid -> 1 bit/cell (256 KB, L2-resident; 8 MB source read is
// nontemporal). Cell c -> bit c little-endian so uint32 read at [c>>5].
// ---------------------------------------------------------------------------
__global__ __launch_bounds__(256)
void pack_word(const unsigned int* __restrict__ occ, unsigned long long* __restrict__ bits) {
    const int idx = blockIdx.x * 256 + threadIdx.x;
    const unsigned int v = __builtin_nontemporal_load(occ + idx);
    const unsigned long long b = __ballot(v != 0u);
    if ((threadIdx.x & 63) == 0) bits[idx >> 6] = b;
}

__global__ __launch_bounds__(256)
void pack_flag(const void* __restrict__ occ, const int* __restrict__ flag_p,
               unsigned long long* __restrict__ bits) {
    const int m = flag_p[0];
    const int idx = blockIdx.x * 256 + threadIdx.x;
    bool v;
    if (m == 2) v = ((const unsigned char*)occ)[idx] != 0;
    else        v = __builtin_nontemporal_load(((const unsigned int*)occ) + idx) != 0u;
    const unsigned long long b = __ballot(v);
    if ((threadIdx.x & 63) == 0) bits[idx >> 6] = b;
}

// ---------------------------------------------------------------------------
// Kernel 1: PERSISTENT blocks — 1024 blocks x 512 threads, grid-stride over
// rays (16 rays/block). Per-ray body is byte-identical to the round-2/6
// passing kernel (one thread per step); the only structural additions are the
// outer loop, a loop-end barrier protecting LDS reuse, and hoisting of
// ray-independent values (start/end/mid, aabb deltas, epilogue mapping).
// All mul+add chains feeding comparisons use _rn intrinsics (numpy ref = no
// FMA contraction) — DO NOT change the FP math: a single flipped boolean
// shifts every downstream offset.
// NOTE (rounds 3-5): the wave-per-ray restructure (4096x256, 8 samples/lane)
// failed output-4 validation with counts==0 under THREE different count
// mechanisms while outputs 0-3 passed. Root cause never identified. Do not
// re-attempt without disasm access. Count path here stays the PROVEN one:
// ballot -> wcount LDS -> thread-0 sum after __syncthreads, written last.
// ---------------------------------------------------------------------------
__global__ __launch_bounds__(512)
void sample_kernel(const float* __restrict__ rays_o, const float* __restrict__ rays_d,
                   const float* __restrict__ aabb, const void* __restrict__ occ,
                   int mode, const int* __restrict__ flag_p,
                   const unsigned int* __restrict__ bits, int use_bits,
                   float* __restrict__ out, int* __restrict__ counts)
{
    const int s = threadIdx.x;

    const float a0x = aabb[0], a0y = aabb[1], a0z = aabb[2];
    const float a1x = aabb[3], a1y = aabb[4], a1z = aabb[5];
    const float ex = __fsub_rn(a1x, a0x);
    const float ey = __fsub_rn(a1y, a0y);
    const float ez = __fsub_rn(a1z, a0z);

    const float step_f = (float)((3.0 - 0.05) / 512.0);
    const float start = __fadd_rn(0.05f, __fmul_rn((float)s, step_f));
    const float end   = __fadd_rn(0.05f, __fmul_rn((float)(s + 1), step_f));
    const float mid   = __fmul_rn(0.5f, __fadd_rn(start, end));

    // epilogue mapping (ray-independent)
    const int grp = s >> 7;    // wave-uniform (boundaries at multiples of 64)
    const int t = s & 127;

    __shared__ __align__(16) float so[1536];   // 512 samples * 3 comps
    __shared__ __align__(16) float sd[1536];
    __shared__ float lmask[512];
    __shared__ int wcount[8];

    for (int r = blockIdx.x; r < N_RAYS; r += SAMPLE_GRID) {

        const float ox = rays_o[3 * r + 0], oy = rays_o[3 * r + 1], oz = rays_o[3 * r + 2];
        const float dx = rays_d[3 * r + 0], dy = rays_d[3 * r + 1], dz = rays_d[3 * r + 2];

        // safe_d = where(|d| > 1e-10, d, 1e-10); inv = 1/safe_d (IEEE divide)
        const float sdx = (fabsf(dx) > 1e-10f) ? dx : 1e-10f;
        const float sdy = (fabsf(dy) > 1e-10f) ? dy : 1e-10f;
        const float sdz = (fabsf(dz) > 1e-10f) ? dz : 1e-10f;
        const float invx = __fdiv_rn(1.0f, sdx);
        const float invy = __fdiv_rn(1.0f, sdy);
        const float invz = __fdiv_rn(1.0f, sdz);

        const float t0x = __fmul_rn(__fsub_rn(a0x, ox), invx);
        const float t1x = __fmul_rn(__fsub_rn(a1x, ox), invx);
        const float t0y = __fmul_rn(__fsub_rn(a0y, oy), invy);
        const float t1y = __fmul_rn(__fsub_rn(a1y, oy), invy);
        const float t0z = __fmul_rn(__fsub_rn(a0z, oz), invz);
        const float t1z = __fmul_rn(__fsub_rn(a1z, oz), invz);

        const float tmin = fmaxf(fmaxf(fmaxf(fminf(t0x, t1x), fminf(t0y, t1y)), fminf(t0z, t1z)), 0.05f);
        const float tmax = fminf(fminf(fminf(fmaxf(t0x, t1x), fmaxf(t0y, t1y)), fmaxf(t0z, t1z)), 3.0f);

        // pos = o + d*mid  (no FMA)
        const float px = __fadd_rn(ox, __fmul_rn(dx, mid));
        const float py = __fadd_rn(oy, __fmul_rn(dy, mid));
        const float pz = __fadd_rn(oz, __fmul_rn(dz, mid));

        // scale = (pos - aabb0) / (aabb1 - aabb0)
        const float scx = __fdiv_rn(__fsub_rn(px, a0x), ex);
        const float scy = __fdiv_rn(__fsub_rn(py, a0y), ey);
        const float scz = __fdiv_rn(__fsub_rn(pz, a0z), ez);

        const bool inside = (scx >= 0.0f) && (scx < 1.0f) &&
                            (scy >= 0.0f) && (scy < 1.0f) &&
                            (scz >= 0.0f) && (scz < 1.0f);
        const bool geom = inside && (start >= tmin) && (end <= tmax);

        bool valid = false;
        if (geom) {
            int gx = (int)__fmul_rn(scx, (float)GRID_R);
            int gy = (int)__fmul_rn(scy, (float)GRID_R);
            int gz = (int)__fmul_rn(scz, (float)GRID_R);
            gx = min(max(gx, 0), GRID_R - 1);
            gy = min(max(gy, 0), GRID_R - 1);
            gz = min(max(gz, 0), GRID_R - 1);
            const int lin = (gx * GRID_R + gy) * GRID_R + gz;
            if (use_bits) {
                valid = (bits[lin >> 5] >> (lin & 31)) & 1u;
            } else {
                const int m = (mode >= 0) ? mode : flag_p[0];
                if (m == 2) valid = ((const unsigned char*)occ)[lin] != 0;
                else        valid = ((const unsigned int*)occ)[lin] != 0u;
            }
        }

        // ---- stage masked origins/dirs (sample-major) + mask into LDS ------
        const float m = valid ? 1.0f : 0.0f;
        lmask[s] = m;
        // stride-3 word writes: 64 lanes -> 2 lanes/bank (free, gcd(3,32)=1)
        so[3 * s + 0] = __fmul_rn(m, ox);
        so[3 * s + 1] = __fmul_rn(m, oy);
        so[3 * s + 2] = __fmul_rn(m, oz);
        sd[3 * s + 0] = __fmul_rn(m, dx);
        sd[3 * s + 1] = __fmul_rn(m, dy);
        sd[3 * s + 2] = __fmul_rn(m, dz);

        const unsigned long long b = __ballot(valid);
        if ((s & 63) == 0) wcount[s >> 6] = __popcll(b);
        __syncthreads();

        // ---- origins & dirs: 384 aligned float4 reads from LDS, nt stores --
        if (s < 384) {
            const f4v vo = ((const f4v*)so)[s];
            const f4v vd = ((const f4v*)sd)[s];
            __builtin_nontemporal_store(vo, (f4v*)out + (long)r * 384 + s);
            __builtin_nontemporal_store(vd, (f4v*)(out + 3L * NS) + (long)r * 384 + s);
        }

        // ---- s_flat / e_flat / ray_indices / mask: one float4 per thread ---
        {
            f4v v;
#pragma unroll
            for (int k = 0; k < 4; ++k) {
                const int smp = 4 * t + k;
                const float mm = lmask[smp];
                float val;
                if (grp == 0)      val = __fmul_rn(mm, __fadd_rn(0.05f, __fmul_rn((float)smp, step_f)));
                else if (grp == 1) val = __fmul_rn(mm, __fadd_rn(0.05f, __fmul_rn((float)(smp + 1), step_f)));
                else if (grp == 2) val = (float)r;
                else               val = mm;
                v[k] = val;
            }
            float* basep;
            if (grp == 0)      basep = out + 6L * NS;                          // s_flat
            else if (grp == 1) basep = out + 7L * NS;                          // e_flat
            else if (grp == 2) basep = out + 8L * NS + 2L * N_RAYS;            // ray_indices
            else               basep = out + 8L * NS + 2L * N_RAYS + (long)NS; // mask
            __builtin_nontemporal_store(v, (f4v*)basep + (long)r * 128 + t);
        }

        if (s == 0) {
            int tt = 0;
#pragma unroll
            for (int w = 0; w < 8; ++w) tt += wcount[w];
            counts[r] = tt;  // normal store: scan_kernel re-reads this
        }

        __syncthreads();   // protect LDS (so/sd/lmask/wcount) reuse next ray
    }
}

// ---------------------------------------------------------------------------
// Kernel 2: exclusive scan of 16384 counts -> packed_info as floats.
// Wave-shuffle scan: 2 barriers total. int4 loads, nt float4 stores.
// ---------------------------------------------------------------------------
__global__ __launch_bounds__(1024)
void scan_kernel(const int* __restrict__ counts, float* __restrict__ packed)
{
    __shared__ int wsum[16];
    const int tid = threadIdx.x;
    const int lane = tid & 63;
    const int w = tid >> 6;

    i4v c4[4];
#pragma unroll
    for (int j = 0; j < 4; ++j) c4[j] = ((const i4v*)counts)[tid * 4 + j];
    int c[16];
#pragma unroll
    for (int j = 0; j < 4; ++j) {
#pragma unroll
        for (int k = 0; k < 4; ++k) c[4 * j + k] = c4[j][k];
    }

    int sum = 0;
#pragma unroll
    for (int i = 0; i < 16; ++i) sum += c[i];

    // inclusive wave scan of per-thread sums
    int incl = sum;
#pragma unroll
    for (int off = 1; off < 64; off <<= 1) {
        const int v = __shfl_up(incl, off, 64);
        if (lane >= off) incl += v;
    }
    if (lane == 63) wsum[w] = incl;
    __syncthreads();

    // wave 0 turns 16 wave totals into exclusive wave offsets
    if (w == 0 && lane < 16) {
        const int v = wsum[lane];
        int iv = v;
#pragma unroll
        for (int off = 1; off < 16; off <<= 1) {
            const int t = __shfl_up(iv, off, 64);
            if (lane >= off) iv += t;
        }
        wsum[lane] = iv - v;  // exclusive
    }
    __syncthreads();

    int run = wsum[w] + (incl - sum);  // exclusive prefix of this thread's chunk
#pragma unroll
    for (int i = 0; i < 16; i += 2) {
        f4v v;
        v[0] = (float)run; v[1] = (float)c[i];     run += c[i];
        v[2] = (float)run; v[3] = (float)c[i + 1]; run += c[i + 1];
        __builtin_nontemporal_store(v, (f4v*)packed + 8 * tid + i / 2);
    }
}

extern "C" void kernel_launch(void* const* d_in, const int* in_sizes, int n_in,
                              void* d_out, int out_size, void* d_ws, size_t ws_size,
                              hipStream_t stream) {
    const float* rays_o = (const float*)d_in[0];
    const float* rays_d = (const float*)d_in[1];
    const float* aabb   = (const float*)d_in[2];
    const void*  occ    = d_in[3];
    float* out = (float*)d_out;

    int* flag   = (int*)d_ws;
    int* counts = (int*)((char*)d_ws + WS_COUNTS_OFF);
    unsigned long long* bits64 = (unsigned long long*)((char*)d_ws + WS_BITS_OFF);
    const int use_bits = (ws_size >= (size_t)WS_NEEDED) ? 1 : 0;

    // Host-side dtype resolution: 4*N_CELLS bytes => 4-byte elements, and
    // `word != 0` is correct for BOTH int32 0/1 and float32 0.0/1.0 storage.
    const long long osz = (long long)in_sizes[3];
    const int mode = (osz == 4LL * N_CELLS) ? 0 : -1;

    if (mode < 0) detect_bw<<<1, 256, 0, stream>>>((const unsigned int*)occ, flag);
    if (use_bits) {
        if (mode == 0) pack_word<<<N_CELLS / 256, 256, 0, stream>>>((const unsigned int*)occ, bits64);
        else           pack_flag<<<N_CELLS / 256, 256, 0, stream>>>(occ, flag, bits64);
    }
    sample_kernel<<<SAMPLE_GRID, 512, 0, stream>>>(rays_o, rays_d, aabb, occ, mode, flag,
                                                   (const unsigned int*)bits64, use_bits,
                                                   out, counts);
    scan_kernel<<<1, 1024, 0, stream>>>(counts, out + 8L * NS);
}

// Round 8
// 344.715 us; speedup vs baseline: 1.0365x; 1.0365x over previous
//
#include <hip/hip_runtime.h>

#define N_RAYS 16384
#define MAX_STEPS 512
#define GRID_R 128
#define N_CELLS (GRID_R * GRID_R * GRID_R) /* 2097152 */
#define NS (N_RAYS * MAX_STEPS)            /* 8388608 samples */

// ws layout (bytes):
//   [0)       flag (1 int)
//   [1024)    counts (16384 ints = 65536 B)
//   [131072)  bit grid (N_CELLS/8 = 262144 B)
#define WS_COUNTS_OFF 1024
#define WS_BITS_OFF 131072
#define WS_NEEDED (WS_BITS_OFF + N_CELLS / 8)

typedef float f4v __attribute__((ext_vector_type(4)));
typedef int   i4v __attribute__((ext_vector_type(4)));

// ---------------------------------------------------------------------------
// Fallback detect (only launched when in_sizes[3] is ambiguous, i.e. not
// 4*N_CELLS bytes). flag: 0 = 4-byte words, 2 = bytes.
// ---------------------------------------------------------------------------
__global__ void detect_bw(const unsigned int* __restrict__ occ, int* __restrict__ flag) {
    __shared__ int okw;
    if (threadIdx.x == 0) okw = 1;
    __syncthreads();
    for (int i = threadIdx.x; i < 1024; i += blockDim.x) {
        const unsigned int v = occ[i];
        if (v != 0u && v != 1u && v != 0x3f800000u) atomicAnd(&okw, 0);
    }
    __syncthreads();
    if (threadIdx.x == 0) flag[0] = okw ? 0 : 2;
}

// ---------------------------------------------------------------------------
// Compress occ grid -> 1 bit/cell (256 KB, L2-resident; 8 MB source read is
// nontemporal). Cell c -> bit c little-endian so uint32 read at [c>>5].
// ---------------------------------------------------------------------------
__global__ __launch_bounds__(256)
void pack_word(const unsigned int* __restrict__ occ, unsigned long long* __restrict__ bits) {
    const int idx = blockIdx.x * 256 + threadIdx.x;
    const unsigned int v = __builtin_nontemporal_load(occ + idx);
    const unsigned long long b = __ballot(v != 0u);
    if ((threadIdx.x & 63) == 0) bits[idx >> 6] = b;
}

__global__ __launch_bounds__(256)
void pack_flag(const void* __restrict__ occ, const int* __restrict__ flag_p,
               unsigned long long* __restrict__ bits) {
    const int m = flag_p[0];
    const int idx = blockIdx.x * 256 + threadIdx.x;
    bool v;
    if (m == 2) v = ((const unsigned char*)occ)[idx] != 0;
    else        v = __builtin_nontemporal_load(((const unsigned int*)occ) + idx) != 0u;
    const unsigned long long b = __ballot(v);
    if ((threadIdx.x & 63) == 0) bits[idx >> 6] = b;
}

// ---------------------------------------------------------------------------
// Kernel 1: one block per ray, one thread per step.  FINAL (round-6 revert).
// All mul+add chains feeding comparisons use _rn intrinsics (numpy ref = no
// FMA contraction) — DO NOT change the FP math: a single flipped boolean
// shifts every downstream offset.
// Epilogue: origins/dirs staged through LDS in sample-major layout (stride-3
// writes are bank-conflict-free: 3 coprime 32; readback is aligned
// ds_read_b128). All output stores nontemporal.
// SESSION LEDGER (falsified theories — do not re-attempt blind):
//   R0 nt-stores/L2-thrash: -3 us. R1 epilogue-VALU LDS staging: -2 us.
//   R3-5 wave-per-ray (4096x256, 8 samples/lane): output-4 counts==0 under
//        THREE count mechanisms while outputs 0-3 passed; root cause never
//        identified without disasm access.
//   R7 persistent 1024-block grid-stride: +9 us (per-ray barriers serialize
//        phases within a block; independent blocks overlap better).
// counts[r] write stays the LAST statement (round-2 placement).
// ---------------------------------------------------------------------------
__global__ __launch_bounds__(512)
void sample_kernel(const float* __restrict__ rays_o, const float* __restrict__ rays_d,
                   const float* __restrict__ aabb, const void* __restrict__ occ,
                   int mode, const int* __restrict__ flag_p,
                   const unsigned int* __restrict__ bits, int use_bits,
                   float* __restrict__ out, int* __restrict__ counts)
{
    const int r = blockIdx.x;
    const int s = threadIdx.x;

    const float ox = rays_o[3 * r + 0], oy = rays_o[3 * r + 1], oz = rays_o[3 * r + 2];
    const float dx = rays_d[3 * r + 0], dy = rays_d[3 * r + 1], dz = rays_d[3 * r + 2];
    const float a0x = aabb[0], a0y = aabb[1], a0z = aabb[2];
    const float a1x = aabb[3], a1y = aabb[4], a1z = aabb[5];

    // safe_d = where(|d| > 1e-10, d, 1e-10); inv = 1/safe_d (IEEE divide)
    const float sdx = (fabsf(dx) > 1e-10f) ? dx : 1e-10f;
    const float sdy = (fabsf(dy) > 1e-10f) ? dy : 1e-10f;
    const float sdz = (fabsf(dz) > 1e-10f) ? dz : 1e-10f;
    const float invx = __fdiv_rn(1.0f, sdx);
    const float invy = __fdiv_rn(1.0f, sdy);
    const float invz = __fdiv_rn(1.0f, sdz);

    const float t0x = __fmul_rn(__fsub_rn(a0x, ox), invx);
    const float t1x = __fmul_rn(__fsub_rn(a1x, ox), invx);
    const float t0y = __fmul_rn(__fsub_rn(a0y, oy), invy);
    const float t1y = __fmul_rn(__fsub_rn(a1y, oy), invy);
    const float t0z = __fmul_rn(__fsub_rn(a0z, oz), invz);
    const float t1z = __fmul_rn(__fsub_rn(a1z, oz), invz);

    const float tmin = fmaxf(fmaxf(fmaxf(fminf(t0x, t1x), fminf(t0y, t1y)), fminf(t0z, t1z)), 0.05f);
    const float tmax = fminf(fminf(fminf(fmaxf(t0x, t1x), fmaxf(t0y, t1y)), fmaxf(t0z, t1z)), 3.0f);

    const float step_f = (float)((3.0 - 0.05) / 512.0);
    const float start = __fadd_rn(0.05f, __fmul_rn((float)s, step_f));
    const float end   = __fadd_rn(0.05f, __fmul_rn((float)(s + 1), step_f));
    const float mid   = __fmul_rn(0.5f, __fadd_rn(start, end));

    // pos = o + d*mid  (no FMA)
    const float px = __fadd_rn(ox, __fmul_rn(dx, mid));
    const float py = __fadd_rn(oy, __fmul_rn(dy, mid));
    const float pz = __fadd_rn(oz, __fmul_rn(dz, mid));

    // scale = (pos - aabb0) / (aabb1 - aabb0)
    const float scx = __fdiv_rn(__fsub_rn(px, a0x), __fsub_rn(a1x, a0x));
    const float scy = __fdiv_rn(__fsub_rn(py, a0y), __fsub_rn(a1y, a0y));
    const float scz = __fdiv_rn(__fsub_rn(pz, a0z), __fsub_rn(a1z, a0z));

    const bool inside = (scx >= 0.0f) && (scx < 1.0f) &&
                        (scy >= 0.0f) && (scy < 1.0f) &&
                        (scz >= 0.0f) && (scz < 1.0f);
    const bool geom = inside && (start >= tmin) && (end <= tmax);

    bool valid = false;
    if (geom) {
        int gx = (int)__fmul_rn(scx, (float)GRID_R);
        int gy = (int)__fmul_rn(scy, (float)GRID_R);
        int gz = (int)__fmul_rn(scz, (float)GRID_R);
        gx = min(max(gx, 0), GRID_R - 1);
        gy = min(max(gy, 0), GRID_R - 1);
        gz = min(max(gz, 0), GRID_R - 1);
        const int lin = (gx * GRID_R + gy) * GRID_R + gz;
        if (use_bits) {
            valid = (bits[lin >> 5] >> (lin & 31)) & 1u;
        } else {
            const int m = (mode >= 0) ? mode : flag_p[0];
            if (m == 2) valid = ((const unsigned char*)occ)[lin] != 0;
            else        valid = ((const unsigned int*)occ)[lin] != 0u;
        }
    }

    // ---- stage masked origins/dirs (sample-major) + mask into LDS ----------
    __shared__ __align__(16) float so[1536];   // 512 samples * 3 comps
    __shared__ __align__(16) float sd[1536];
    __shared__ float lmask[512];
    __shared__ int wcount[8];

    const float m = valid ? 1.0f : 0.0f;
    lmask[s] = m;
    // stride-3 word writes: 64 lanes -> 2 lanes/bank (free, gcd(3,32)=1)
    so[3 * s + 0] = __fmul_rn(m, ox);
    so[3 * s + 1] = __fmul_rn(m, oy);
    so[3 * s + 2] = __fmul_rn(m, oz);
    sd[3 * s + 0] = __fmul_rn(m, dx);
    sd[3 * s + 1] = __fmul_rn(m, dy);
    sd[3 * s + 2] = __fmul_rn(m, dz);

    const unsigned long long b = __ballot(valid);
    if ((s & 63) == 0) wcount[s >> 6] = __popcll(b);
    __syncthreads();

    // ---- origins & dirs: 384 aligned float4 reads from LDS, nt stores -----
    if (s < 384) {
        const f4v vo = ((const f4v*)so)[s];
        const f4v vd = ((const f4v*)sd)[s];
        __builtin_nontemporal_store(vo, (f4v*)out + (long)r * 384 + s);
        __builtin_nontemporal_store(vd, (f4v*)(out + 3L * NS) + (long)r * 384 + s);
    }

    // ---- s_flat / e_flat / ray_indices / mask: one float4 per thread ----
    {
        const int grp = s >> 7;    // wave-uniform (boundaries at multiples of 64)
        const int t = s & 127;
        f4v v;
#pragma unroll
        for (int k = 0; k < 4; ++k) {
            const int smp = 4 * t + k;
            const float mm = lmask[smp];
            float val;
            if (grp == 0)      val = __fmul_rn(mm, __fadd_rn(0.05f, __fmul_rn((float)smp, step_f)));
            else if (grp == 1) val = __fmul_rn(mm, __fadd_rn(0.05f, __fmul_rn((float)(smp + 1), step_f)));
            else if (grp == 2) val = (float)r;
            else               val = mm;
            v[k] = val;
        }
        float* basep;
        if (grp == 0)      basep = out + 6L * NS;                          // s_flat
        else if (grp == 1) basep = out + 7L * NS;                          // e_flat
        else if (grp == 2) basep = out + 8L * NS + 2L * N_RAYS;            // ray_indices
        else               basep = out + 8L * NS + 2L * N_RAYS + (long)NS; // mask
        __builtin_nontemporal_store(v, (f4v*)basep + (long)r * 128 + t);
    }

    if (s == 0) {
        int t = 0;
#pragma unroll
        for (int w = 0; w < 8; ++w) t += wcount[w];
        counts[r] = t;  // normal store: scan_kernel re-reads this; stays LAST
    }
}

// ---------------------------------------------------------------------------
// Kernel 2: exclusive scan of 16384 counts -> packed_info as floats.
// Wave-shuffle scan: 2 barriers total. int4 loads, nt float4 stores.
// ---------------------------------------------------------------------------
__global__ __launch_bounds__(1024)
void scan_kernel(const int* __restrict__ counts, float* __restrict__ packed)
{
    __shared__ int wsum[16];
    const int tid = threadIdx.x;
    const int lane = tid & 63;
    const int w = tid >> 6;

    i4v c4[4];
#pragma unroll
    for (int j = 0; j < 4; ++j) c4[j] = ((const i4v*)counts)[tid * 4 + j];
    int c[16];
#pragma unroll
    for (int j = 0; j < 4; ++j) {
#pragma unroll
        for (int k = 0; k < 4; ++k) c[4 * j + k] = c4[j][k];
    }

    int sum = 0;
#pragma unroll
    for (int i = 0; i < 16; ++i) sum += c[i];

    // inclusive wave scan of per-thread sums
    int incl = sum;
#pragma unroll
    for (int off = 1; off < 64; off <<= 1) {
        const int v = __shfl_up(incl, off, 64);
        if (lane >= off) incl += v;
    }
    if (lane == 63) wsum[w] = incl;
    __syncthreads();

    // wave 0 turns 16 wave totals into exclusive wave offsets
    if (w == 0 && lane < 16) {
        const int v = wsum[lane];
        int iv = v;
#pragma unroll
        for (int off = 1; off < 16; off <<= 1) {
            const int t = __shfl_up(iv, off, 64);
            if (lane >= off) iv += t;
        }
        wsum[lane] = iv - v;  // exclusive
    }
    __syncthreads();

    int run = wsum[w] + (incl - sum);  // exclusive prefix of this thread's chunk
#pragma unroll
    for (int i = 0; i < 16; i += 2) {
        f4v v;
        v[0] = (float)run; v[1] = (float)c[i];     run += c[i];
        v[2] = (float)run; v[3] = (float)c[i + 1]; run += c[i + 1];
        __builtin_nontemporal_store(v, (f4v*)packed + 8 * tid + i / 2);
    }
}

extern "C" void kernel_launch(void* const* d_in, const int* in_sizes, int n_in,
                              void* d_out, int out_size, void* d_ws, size_t ws_size,
                              hipStream_t stream) {
    const float* rays_o = (const float*)d_in[0];
    const float* rays_d = (const float*)d_in[1];
    const float* aabb   = (const float*)d_in[2];
    const void*  occ    = d_in[3];
    float* out = (float*)d_out;

    int* flag   = (int*)d_ws;
    int* counts = (int*)((char*)d_ws + WS_COUNTS_OFF);
    unsigned long long* bits64 = (unsigned long long*)((char*)d_ws + WS_BITS_OFF);
    const int use_bits = (ws_size >= (size_t)WS_NEEDED) ? 1 : 0;

    // Host-side dtype resolution: 4*N_CELLS bytes => 4-byte elements, and
    // `word != 0` is correct for BOTH int32 0/1 and float32 0.0/1.0 storage.
    const long long osz = (long long)in_sizes[3];
    const int mode = (osz == 4LL * N_CELLS) ? 0 : -1;

    if (mode < 0) detect_bw<<<1, 256, 0, stream>>>((const unsigned int*)occ, flag);
    if (use_bits) {
        if (mode == 0) pack_word<<<N_CELLS / 256, 256, 0, stream>>>((const unsigned int*)occ, bits64);
        else           pack_flag<<<N_CELLS / 256, 256, 0, stream>>>(occ, flag, bits64);
    }
    sample_kernel<<<N_RAYS, 512, 0, stream>>>(rays_o, rays_d, aabb, occ, mode, flag,
                                              (const unsigned int*)bits64, use_bits,
                                              out, counts);
    scan_kernel<<<1, 1024, 0, stream>>>(counts, out + 8L * NS);
}